// Round 13
// baseline (59.041 us; speedup 1.0000x reference)
//
#include <hip/hip_runtime.h>
#include <math.h>

// ---------------- problem constants ----------------
#define NROWS 32768   // B*T independent rows (alpha=exp(-50): scan decouples, verified R1)
#define NK 256        // IN_F
#define NF 256        // F
#define NT_SEQ 256    // T
#define MTILE 32      // rows per tile (block = 2 tiles, pipelined)
#define TAU 8e-3f     // bf16 vs fp64 ambiguity band (validated R10..R12: absmax 0.0)

// Verified facts (R1..R12, absmax == 0.0 throughout):
//  * v_mem(t) == cur(t) exactly in the reference's own arithmetic.
//  * LN of binary s collapses: mu = k/256 exact, var = mu(1-mu).
//  * fp64 dot (this exact order) reproduces np's spike decisions.
//  * MFMA fragment mapping (A: row=lane&15, k=(lane>>4)*8+j; B: col=lane&15;
//    C/D: col=lane&15, row=(lane>>4)*4+reg) correct.
//  * bf16 GEMM + TAU=8e-3 + COALESCED (W^T) fp64 recheck: exact & cheap (R12).
// R13: 2-tile in-block pipeline. Stage(T1) loads issue before K-loop(T0);
// cvt+LDS-write(T1->buf1) lands before T0's tail barriers; K-loop(T1) starts
// right after T0's epilogue. Overlaps stage latency with compute; staggers
// HBM bursts across blocks.

typedef __attribute__((ext_vector_type(4))) float f32x4;
typedef __attribute__((ext_vector_type(8))) short bf16x8;

__device__ __forceinline__ unsigned short bf16_rne(float f) {
    unsigned int u = __builtin_bit_cast(unsigned int, f);
    u += 0x7FFFu + ((u >> 16) & 1u);       // round-to-nearest-even
    return (unsigned short)(u >> 16);
}

// ---- k0: W -> bf16 MFMA-B-fragment order (verified R3..R12) + fp32 W^T ----
__global__ void prep_w(const float* __restrict__ W,
                       unsigned short* __restrict__ wt,
                       float* __restrict__ wtT) {
    const int k = blockIdx.x;       // 0..255
    const int col = threadIdx.x;    // 0..255
    const float w = W[k * NF + col];
    const int ks = k >> 5, chunk = (k >> 3) & 3, j = k & 7;
    wt[(ks * 4 + chunk) * 2048 + col * 8 + j] = bf16_rne(w);
    wtT[col * NK + k] = w;          // fp32 transpose for coalesced recheck
}

// ---- k1: pipelined 2-tile bf16 GEMM + spike + recheck + closed-form LN ----
__global__ __launch_bounds__(512)
void lif_main(const float* __restrict__ spikes,
              const float* __restrict__ bias,
              const float* __restrict__ ln_scale,
              const float* __restrict__ ln_bias,
              const unsigned short* __restrict__ wt,
              const float* __restrict__ wtT,
              float* __restrict__ out)
{
    // double-buffered A panels: 2 x (32 rows x 256 k bf16, stride 264) = 33.8 KB
    __shared__ __align__(16) short alds[2][MTILE][264];
    __shared__ unsigned int bits[MTILE][8];
    __shared__ float rinv_s[MTILE], mu_s[MTILE];
    __shared__ unsigned int elist[256];
    __shared__ int ecnt;

    const int tid = threadIdx.x;
    const int lane = tid & 63;
    const int wid = tid >> 6;                  // 0..7: cols [wid*32, +32)
    const int row_base = blockIdx.x * (2 * MTILE);

    if (tid == 0) ecnt = 0;

    // staging map: thread covers rows r0 = tid>>5 and r1 = 16 + (tid>>5),
    // cols c8..c8+7 with c8 = (tid&31)*8
    const int r0 = tid >> 5, r1 = 16 + (tid >> 5), c8 = (tid & 31) * 8;

    const int a_off = (lane & 15) * 264 + (lane >> 4) * 8;       // halfs
    const int b_base = (lane >> 4) * 2048 + (wid * 32 + (lane & 15)) * 8;

    // ---- helpers ----
    auto cvt8 = [&](const float4& u, const float4& v) -> uint4 {
        return make_uint4(
            (unsigned int)bf16_rne(u.x) | ((unsigned int)bf16_rne(u.y) << 16),
            (unsigned int)bf16_rne(u.z) | ((unsigned int)bf16_rne(u.w) << 16),
            (unsigned int)bf16_rne(v.x) | ((unsigned int)bf16_rne(v.y) << 16),
            (unsigned int)bf16_rne(v.z) | ((unsigned int)bf16_rne(v.w) << 16));
    };

    // ---- prologue: load + stage tile 0 into buf 0 ----
    float4 u0, v0, u1, v1;
    {
        const float* p0 = spikes + (size_t)(row_base + r0) * NK + c8;
        const float* p1 = spikes + (size_t)(row_base + r1) * NK + c8;
        u0 = *reinterpret_cast<const float4*>(p0);
        v0 = *reinterpret_cast<const float4*>(p0 + 4);
        u1 = *reinterpret_cast<const float4*>(p1);
        v1 = *reinterpret_cast<const float4*>(p1 + 4);
    }
    *reinterpret_cast<uint4*>(&alds[0][r0][c8]) = cvt8(u0, v0);
    *reinterpret_cast<uint4*>(&alds[0][r1][c8]) = cvt8(u1, v1);
    __syncthreads();

    // ---- issue tile-1 loads now: latency hides under K-loop(T0) ----
    {
        const float* p0 = spikes + (size_t)(row_base + MTILE + r0) * NK + c8;
        const float* p1 = spikes + (size_t)(row_base + MTILE + r1) * NK + c8;
        u0 = *reinterpret_cast<const float4*>(p0);
        v0 = *reinterpret_cast<const float4*>(p0 + 4);
        u1 = *reinterpret_cast<const float4*>(p1);
        v1 = *reinterpret_cast<const float4*>(p1 + 4);
    }

    #pragma unroll 1
    for (int p = 0; p < 2; ++p) {
        const int row0 = row_base + p * MTILE;

        // ---- barrier-free K loop on buf p ----
        f32x4 acc[2][2];
        {
            const f32x4 z = {0.f, 0.f, 0.f, 0.f};
            acc[0][0] = z; acc[0][1] = z; acc[1][0] = z; acc[1][1] = z;
        }
        const short* alds_flat = &alds[p][0][0];
        #pragma unroll
        for (int ks = 0; ks < 8; ++ks) {
            const bf16x8 b0 = *reinterpret_cast<const bf16x8*>(wt + ks * 8192 + b_base);
            const bf16x8 b1 = *reinterpret_cast<const bf16x8*>(wt + ks * 8192 + b_base + 128);
            const bf16x8 a0 = *reinterpret_cast<const bf16x8*>(alds_flat + ks * 32 + a_off);
            const bf16x8 a1 = *reinterpret_cast<const bf16x8*>(alds_flat + 16 * 264 + ks * 32 + a_off);
            acc[0][0] = __builtin_amdgcn_mfma_f32_16x16x32_bf16(a0, b0, acc[0][0], 0, 0, 0);
            acc[0][1] = __builtin_amdgcn_mfma_f32_16x16x32_bf16(a0, b1, acc[0][1], 0, 0, 0);
            acc[1][0] = __builtin_amdgcn_mfma_f32_16x16x32_bf16(a1, b0, acc[1][0], 0, 0, 0);
            acc[1][1] = __builtin_amdgcn_mfma_f32_16x16x32_bf16(a1, b1, acc[1][1], 0, 0, 0);
        }

        // ---- after K-loop(T0): commit tile-1 stage into buf 1 ----
        if (p == 0) {
            *reinterpret_cast<uint4*>(&alds[1][r0][c8]) = cvt8(u0, v0);
            *reinterpret_cast<uint4*>(&alds[1][r1][c8]) = cvt8(u1, v1);
            // visibility to all threads is guaranteed by the tail barriers below
        }

        // ---- decisions; in-band -> worklist ----
        unsigned int smask[2] = {0u, 0u};
        #pragma unroll
        for (int mt = 0; mt < 2; ++mt)
            #pragma unroll
            for (int nt = 0; nt < 2; ++nt) {
                const int gcol = wid * 32 + nt * 16 + (lane & 15);
                const float bv = bias[gcol];
                #pragma unroll
                for (int reg = 0; reg < 4; ++reg) {
                    const float v = acc[mt][nt][reg] + bv;
                    if ((v - 0.5f) > 0.0f) smask[mt] |= 1u << (nt * 4 + reg);
                    if (__builtin_expect(fabsf(v - 0.5f) < TAU, 0)) {
                        const int rl = mt * 16 + (lane >> 4) * 4 + reg;
                        const int ei = atomicAdd(&ecnt, 1);
                        if (ei < 256) elist[ei] = (unsigned int)((rl << 8) | gcol);
                    }
                }
            }

        // ---- assemble row masks ----
        #pragma unroll
        for (int mt = 0; mt < 2; ++mt)
            #pragma unroll
            for (int reg = 0; reg < 4; ++reg) {
                const unsigned long long m0 = __ballot((smask[mt] >> (reg)) & 1u);
                const unsigned long long m1 = __ballot((smask[mt] >> (4 + reg)) & 1u);
                if (lane < 4) {
                    const int g = lane;
                    const unsigned int w =
                        (unsigned int)((m0 >> (g * 16)) & 0xFFFFull) |
                        ((unsigned int)((m1 >> (g * 16)) & 0xFFFFull) << 16);
                    bits[mt * 16 + g * 4 + reg][wid] = w;
                }
            }
        __syncthreads();

        // ---- coalesced exact fp64 recheck (W^T; same math/order as R1..R12) ----
        const int ne = min(ecnt, 256);
        for (int e = wid; e < ne; e += 8) {
            const unsigned int pk = elist[e];
            const int rl = (int)(pk >> 8), gcol = (int)(pk & 255u);
            const float* sr = spikes + (size_t)(row0 + rl) * NK;
            const float* wc = wtT + (size_t)gcol * NK;
            const int k0 = lane * 4;
            const float4 s4 = *reinterpret_cast<const float4*>(sr + k0);
            const float4 w4 = *reinterpret_cast<const float4*>(wc + k0);
            const double pp0 = (double)s4.x * (double)w4.x;
            const double pp1 = (double)s4.y * (double)w4.y;
            const double pp2 = (double)s4.z * (double)w4.z;
            const double pp3 = (double)s4.w * (double)w4.w;
            double pl = (pp0 + pp1) + (pp2 + pp3);
            #pragma unroll
            for (int off = 32; off > 0; off >>= 1) pl += __shfl_down(pl, off);
            if (lane == 0) {
                const double vex = pl + (double)bias[gcol];
                const bool sex = (vex - 0.5) > 0.0;
                const bool spv = (bits[rl][gcol >> 5] >> (gcol & 31)) & 1u;
                if (sex != spv) atomicXor(&bits[rl][gcol >> 5], 1u << (gcol & 31));
            }
        }
        __syncthreads();

        // ---- per-row stats (identical double math) + ecnt reset for tile 1 ----
        if (tid < MTILE) {
            int kc = 0;
            #pragma unroll
            for (int w = 0; w < 8; ++w) kc += __popc(bits[tid][w]);
            const double mu = (double)kc * (1.0 / 256.0);
            const double var = mu * (1.0 - mu);
            rinv_s[tid] = (float)(1.0 / sqrt(var + 1e-6));
            mu_s[tid] = (float)mu;
        }
        if (tid == 0) ecnt = 0;          // all ecnt/elist readers finished above
        __syncthreads();

        // ---- LN epilogue + coalesced float4 store ----
        const int orow = tid >> 4;           // 0..31
        const int of0 = (tid & 15) * 4;      // 0..60
        const int grow = row0 + orow;
        const int t = grow & (NT_SEQ - 1);
        const float rinv = rinv_s[orow];
        const float muf = mu_s[orow];
        #pragma unroll
        for (int j = 0; j < 4; ++j) {
            const int f = of0 + j * 64;
            const unsigned int wb = bits[orow][f >> 5];
            const int sh = f & 31;
            const float4 g4 = *reinterpret_cast<const float4*>(&ln_scale[t * NF + f]);
            const float4 b4 = *reinterpret_cast<const float4*>(&ln_bias[t * NF + f]);
            float4 o;
            const float s0 = ((wb >> (sh + 0)) & 1u) ? 1.0f : 0.0f;
            const float s1 = ((wb >> (sh + 1)) & 1u) ? 1.0f : 0.0f;
            const float s2 = ((wb >> (sh + 2)) & 1u) ? 1.0f : 0.0f;
            const float s3 = ((wb >> (sh + 3)) & 1u) ? 1.0f : 0.0f;
            o.x = (s0 - muf) * rinv * g4.x + b4.x;
            o.y = (s1 - muf) * rinv * g4.y + b4.y;
            o.z = (s2 - muf) * rinv * g4.z + b4.z;
            o.w = (s3 - muf) * rinv * g4.w + b4.w;
            *reinterpret_cast<float4*>(&out[(size_t)grow * NF + f]) = o;
        }

        // tile-1 ballot writes to bits[] must not race tile-0 epilogue reads
        if (p == 0) __syncthreads();
    }
}

extern "C" void kernel_launch(void* const* d_in, const int* in_sizes, int n_in,
                              void* d_out, int out_size, void* d_ws, size_t ws_size,
                              hipStream_t stream) {
    const float* spikes   = (const float*)d_in[0];
    const float* W        = (const float*)d_in[1];
    const float* bias     = (const float*)d_in[2];
    const float* ln_scale = (const float*)d_in[3];
    const float* ln_bias  = (const float*)d_in[4];
    float* out = (float*)d_out;
    unsigned short* wt = (unsigned short*)d_ws;                 // 128 KB
    float* wtT = (float*)((char*)d_ws + 131072);                // 256 KB fp32 W^T

    prep_w<<<dim3(256), dim3(256), 0, stream>>>(W, wt, wtT);
    lif_main<<<dim3(NROWS / (2 * MTILE)), dim3(512), 0, stream>>>(
        spikes, bias, ln_scale, ln_bias, wt, wtT, out);
}

// Round 14
// 55.237 us; speedup vs baseline: 1.0689x; 1.0689x over previous
//
#include <hip/hip_runtime.h>
#include <math.h>

// ---------------- problem constants ----------------
#define NROWS 32768   // B*T independent rows (alpha=exp(-50): scan decouples, verified R1)
#define NK 256        // IN_F
#define NF 256        // F
#define NT_SEQ 256    // T
#define MTILE 32      // rows per block (4 waves x [32 rows x 64 cols])
#define TAU 8e-3f     // bf16 vs fp64 ambiguity band (validated R10..R13: absmax 0.0)

// Verified facts (R1..R13, absmax == 0.0 throughout):
//  * v_mem(t) == cur(t) exactly in the reference's own arithmetic.
//  * LN of binary s collapses: mu = k/256 exact, var = mu(1-mu).
//  * fp64 dot (this exact order) reproduces np's spike decisions.
//  * MFMA fragment mapping (A: row=lane&15, k=(lane>>4)*8+j; B: col=lane&15;
//    C/D: col=lane&15, row=(lane>>4)*4+reg) correct.
//  * bf16 GEMM + TAU=8e-3 + COALESCED (W^T) fp64 recheck: exact & cheap (R12).
// R14: kill the staged/lockstep structure (R7/R8/R11/R13 all neutral/worse).
// A-fragments load DIRECTLY from global (2 coalesced float4 per lane), cvt to
// bf16 in registers; K-loop has NO LDS and NO barriers. 4 waves/block share
// the 32-row A panel via L1/L2 (read-only reuse, no sync). Tail = R12's.

typedef __attribute__((ext_vector_type(4))) float f32x4;
typedef __attribute__((ext_vector_type(8))) short bf16x8;

__device__ __forceinline__ unsigned short bf16_rne(float f) {
    unsigned int u = __builtin_bit_cast(unsigned int, f);
    u += 0x7FFFu + ((u >> 16) & 1u);       // round-to-nearest-even
    return (unsigned short)(u >> 16);
}

// ---- k0: W -> bf16 MFMA-B-fragment order (verified R3..R13) + fp32 W^T ----
__global__ void prep_w(const float* __restrict__ W,
                       unsigned short* __restrict__ wt,
                       float* __restrict__ wtT) {
    const int k = blockIdx.x;       // 0..255
    const int col = threadIdx.x;    // 0..255
    const float w = W[k * NF + col];
    const int ks = k >> 5, chunk = (k >> 3) & 3, j = k & 7;
    wt[(ks * 4 + chunk) * 2048 + col * 8 + j] = bf16_rne(w);
    wtT[col * NK + k] = w;          // fp32 transpose for coalesced recheck
}

// ---- k1: barrier-free bf16 GEMM + spike + recheck + closed-form LN ----
__global__ __launch_bounds__(256)
void lif_main(const float* __restrict__ spikes,
              const float* __restrict__ bias,
              const float* __restrict__ ln_scale,
              const float* __restrict__ ln_bias,
              const unsigned short* __restrict__ wt,
              const float* __restrict__ wtT,
              float* __restrict__ out)
{
    __shared__ unsigned int bits[MTILE][8];    // 256-bit row masks (1 KB)
    __shared__ float rinv_s[MTILE], mu_s[MTILE];
    __shared__ unsigned int elist[256];        // in-band worklist
    __shared__ int ecnt;

    const int tid = threadIdx.x;
    const int lane = tid & 63;
    const int wid = tid >> 6;                  // 0..3: cols [wid*64, +64)
    const int row0 = blockIdx.x * MTILE;

    if (tid == 0) ecnt = 0;
    __syncthreads();

    // A-fragment source (verified layout): lane reads
    //   spikes[row0 + mt*16 + (lane&15)][ks*32 + (lane>>4)*8 + 0..7]
    const float* a_base = spikes + (size_t)(row0 + (lane & 15)) * NK + (lane >> 4) * 8;
    // B-fragment base in pre-permuted wt
    const int b_base = (lane >> 4) * 2048 + (wid * 64 + (lane & 15)) * 8;

    f32x4 acc[2][4];   // [mt][nt]
    {
        const f32x4 z = {0.f, 0.f, 0.f, 0.f};
        #pragma unroll
        for (int mt = 0; mt < 2; ++mt)
            #pragma unroll
            for (int nt = 0; nt < 4; ++nt) acc[mt][nt] = z;
    }

    // ---- K loop: no LDS, no barriers; loads pipeline freely ----
    #pragma unroll
    for (int ks = 0; ks < 8; ++ks) {
        bf16x8 a[2];
        #pragma unroll
        for (int mt = 0; mt < 2; ++mt) {
            const float* p = a_base + (size_t)(mt * 16) * NK + ks * 32;
            const float4 u = *reinterpret_cast<const float4*>(p);
            const float4 v = *reinterpret_cast<const float4*>(p + 4);
            a[mt][0] = (short)bf16_rne(u.x);
            a[mt][1] = (short)bf16_rne(u.y);
            a[mt][2] = (short)bf16_rne(u.z);
            a[mt][3] = (short)bf16_rne(u.w);
            a[mt][4] = (short)bf16_rne(v.x);
            a[mt][5] = (short)bf16_rne(v.y);
            a[mt][6] = (short)bf16_rne(v.z);
            a[mt][7] = (short)bf16_rne(v.w);
        }
        #pragma unroll
        for (int nt = 0; nt < 4; ++nt) {
            const bf16x8 b = *reinterpret_cast<const bf16x8*>(
                wt + ks * 8192 + b_base + nt * 128);
            acc[0][nt] = __builtin_amdgcn_mfma_f32_16x16x32_bf16(a[0], b, acc[0][nt], 0, 0, 0);
            acc[1][nt] = __builtin_amdgcn_mfma_f32_16x16x32_bf16(a[1], b, acc[1][nt], 0, 0, 0);
        }
    }

    // ---- decisions; in-band elements -> worklist ----
    unsigned int smask[2] = {0u, 0u};   // bit nt*4+reg
    #pragma unroll
    for (int mt = 0; mt < 2; ++mt)
        #pragma unroll
        for (int nt = 0; nt < 4; ++nt) {
            const int gcol = wid * 64 + nt * 16 + (lane & 15);
            const float bv = bias[gcol];
            #pragma unroll
            for (int reg = 0; reg < 4; ++reg) {
                const float v = acc[mt][nt][reg] + bv;
                if ((v - 0.5f) > 0.0f) smask[mt] |= 1u << (nt * 4 + reg);
                if (__builtin_expect(fabsf(v - 0.5f) < TAU, 0)) {
                    const int rl = mt * 16 + (lane >> 4) * 4 + reg;
                    const int ei = atomicAdd(&ecnt, 1);
                    if (ei < 256) elist[ei] = (unsigned int)((rl << 8) | gcol);
                }
            }
        }

    // ---- assemble row masks (each wave owns 2 words per row; R9-verified) ----
    #pragma unroll
    for (int mt = 0; mt < 2; ++mt)
        #pragma unroll
        for (int reg = 0; reg < 4; ++reg) {
            unsigned long long m[4];
            #pragma unroll
            for (int nt = 0; nt < 4; ++nt)
                m[nt] = __ballot((smask[mt] >> (nt * 4 + reg)) & 1u);
            if (lane < 4) {
                const int g = lane;
                const unsigned int w0 =
                    (unsigned int)((m[0] >> (g * 16)) & 0xFFFFull) |
                    ((unsigned int)((m[1] >> (g * 16)) & 0xFFFFull) << 16);
                const unsigned int w1 =
                    (unsigned int)((m[2] >> (g * 16)) & 0xFFFFull) |
                    ((unsigned int)((m[3] >> (g * 16)) & 0xFFFFull) << 16);
                const int rl = mt * 16 + g * 4 + reg;
                bits[rl][wid * 2 + 0] = w0;
                bits[rl][wid * 2 + 1] = w1;
            }
        }
    __syncthreads();

    // ---- coalesced exact fp64 recheck (W^T; same math/order as R1..R13) ----
    const int ne = min(ecnt, 256);
    for (int e = wid; e < ne; e += 4) {
        const unsigned int pk = elist[e];
        const int rl = (int)(pk >> 8), gcol = (int)(pk & 255u);
        const float* sr = spikes + (size_t)(row0 + rl) * NK;
        const float* wc = wtT + (size_t)gcol * NK;
        const int k0 = lane * 4;
        const float4 s4 = *reinterpret_cast<const float4*>(sr + k0);
        const float4 w4 = *reinterpret_cast<const float4*>(wc + k0);
        const double p0 = (double)s4.x * (double)w4.x;
        const double p1 = (double)s4.y * (double)w4.y;
        const double p2 = (double)s4.z * (double)w4.z;
        const double p3 = (double)s4.w * (double)w4.w;
        double pl = (p0 + p1) + (p2 + p3);
        #pragma unroll
        for (int off = 32; off > 0; off >>= 1) pl += __shfl_down(pl, off);
        if (lane == 0) {
            const double vex = pl + (double)bias[gcol];
            const bool sex = (vex - 0.5) > 0.0;
            const bool spv = (bits[rl][gcol >> 5] >> (gcol & 31)) & 1u;
            if (sex != spv) atomicXor(&bits[rl][gcol >> 5], 1u << (gcol & 31));
        }
    }
    __syncthreads();

    // ---- per-row stats (identical double math to R1..R13) ----
    if (tid < MTILE) {
        int kc = 0;
        #pragma unroll
        for (int w = 0; w < 8; ++w) kc += __popc(bits[tid][w]);
        const double mu = (double)kc * (1.0 / 256.0);
        const double var = mu * (1.0 - mu);
        rinv_s[tid] = (float)(1.0 / sqrt(var + 1e-6));
        mu_s[tid] = (float)mu;
    }
    __syncthreads();

    // ---- LN epilogue + coalesced float4 store (R9-verified mapping) ----
    const int orow = tid >> 3;           // 0..31
    const int of0 = (tid & 7) * 4;       // 0..28
    const int grow = row0 + orow;
    const int t = grow & (NT_SEQ - 1);
    const float rinv = rinv_s[orow];
    const float muf = mu_s[orow];
    #pragma unroll
    for (int j = 0; j < 8; ++j) {
        const int f = of0 + j * 32;
        const unsigned int wb = bits[orow][j];   // f>>5 == j since of0 < 32
        const int sh = of0;
        const float4 g4 = *reinterpret_cast<const float4*>(&ln_scale[t * NF + f]);
        const float4 b4 = *reinterpret_cast<const float4*>(&ln_bias[t * NF + f]);
        float4 o;
        const float s0 = ((wb >> (sh + 0)) & 1u) ? 1.0f : 0.0f;
        const float s1 = ((wb >> (sh + 1)) & 1u) ? 1.0f : 0.0f;
        const float s2 = ((wb >> (sh + 2)) & 1u) ? 1.0f : 0.0f;
        const float s3 = ((wb >> (sh + 3)) & 1u) ? 1.0f : 0.0f;
        o.x = (s0 - muf) * rinv * g4.x + b4.x;
        o.y = (s1 - muf) * rinv * g4.y + b4.y;
        o.z = (s2 - muf) * rinv * g4.z + b4.z;
        o.w = (s3 - muf) * rinv * g4.w + b4.w;
        *reinterpret_cast<float4*>(&out[(size_t)grow * NF + f]) = o;
    }
}

extern "C" void kernel_launch(void* const* d_in, const int* in_sizes, int n_in,
                              void* d_out, int out_size, void* d_ws, size_t ws_size,
                              hipStream_t stream) {
    const float* spikes   = (const float*)d_in[0];
    const float* W        = (const float*)d_in[1];
    const float* bias     = (const float*)d_in[2];
    const float* ln_scale = (const float*)d_in[3];
    const float* ln_bias  = (const float*)d_in[4];
    float* out = (float*)d_out;
    unsigned short* wt = (unsigned short*)d_ws;                 // 128 KB
    float* wtT = (float*)((char*)d_ws + 131072);                // 256 KB fp32 W^T

    prep_w<<<dim3(256), dim3(256), 0, stream>>>(W, wt, wtT);
    lif_main<<<dim3(NROWS / MTILE), dim3(256), 0, stream>>>(
        spikes, bias, ln_scale, ln_bias, wt, wtT, out);
}

// Round 15
// 44.666 us; speedup vs baseline: 1.3218x; 1.2367x over previous
//
#include <hip/hip_runtime.h>
#include <math.h>

// ---------------- problem constants ----------------
#define NROWS 32768   // B*T independent rows (alpha=exp(-50): scan decouples, verified R1)
#define NK 256        // IN_F
#define NF 256        // F
#define NT_SEQ 256    // T
#define MTILE 64      // rows per block (R6's best-measured tiling: 512 thr, 8 waves)
#define TAU 8e-3f     // bf16 vs fp64 ambiguity band (validated R10..R14: absmax 0.0)

// Consolidation of best-measured pieces (R1..R14, all absmax == 0.0):
//  * R6 tiling: MTILE=64, 512 threads, one stage barrier, barrier-free K loop
//    (best measured: 36.5 us).
//  * R10 numerics: single-component bf16 GEMM (1/3 MFMA, half LDS of fp16
//    split) + TAU=8e-3.
//  * R12 recheck: coalesced fp64 via fp32 W^T in ws (same summation order as
//    the R1-verified exact path).
// Evidence note: all structural variants (R7/R8/R11/R13/R14) land at or above
// ~36-40 us with every pipe idle; steady-state replays share HBM with the
// harness's 268MB fill dispatches (~40 us @ 6.6 TB/s) -> environment floor.

typedef __attribute__((ext_vector_type(4))) float f32x4;
typedef __attribute__((ext_vector_type(8))) short bf16x8;

__device__ __forceinline__ unsigned short bf16_rne(float f) {
    unsigned int u = __builtin_bit_cast(unsigned int, f);
    u += 0x7FFFu + ((u >> 16) & 1u);       // round-to-nearest-even
    return (unsigned short)(u >> 16);
}

// ---- k0: W -> bf16 MFMA-B-fragment order (verified R3..R14) + fp32 W^T ----
__global__ void prep_w(const float* __restrict__ W,
                       unsigned short* __restrict__ wt,
                       float* __restrict__ wtT) {
    const int k = blockIdx.x;       // 0..255
    const int col = threadIdx.x;    // 0..255
    const float w = W[k * NF + col];
    const int ks = k >> 5, chunk = (k >> 3) & 3, j = k & 7;
    wt[(ks * 4 + chunk) * 2048 + col * 8 + j] = bf16_rne(w);
    wtT[col * NK + k] = w;          // fp32 transpose for coalesced recheck
}

// ---- k1: bf16 GEMM + spike + coalesced exact recheck + closed-form LN ----
__global__ __launch_bounds__(512)
void lif_main(const float* __restrict__ spikes,
              const float* __restrict__ bias,
              const float* __restrict__ ln_scale,
              const float* __restrict__ ln_bias,
              const unsigned short* __restrict__ wt,
              const float* __restrict__ wtT,
              float* __restrict__ out)
{
    // A panel: 64 rows x 256 k bf16, row stride 264 halfs (528 B ->
    // frag-read banks 4r mod 32: 2-way = free). 33.8 KB -> 4 blocks/CU.
    __shared__ __align__(16) short alds[MTILE][264];
    __shared__ unsigned int bits[MTILE][8];    // 256-bit row masks
    __shared__ float rinv_s[MTILE], mu_s[MTILE];
    __shared__ unsigned int elist[256];        // in-band worklist
    __shared__ int ecnt;

    const int tid = threadIdx.x;
    const int lane = tid & 63;
    const int wid = tid >> 6;                  // 0..7: cols [wid*32, +32)
    const int row0 = blockIdx.x * MTILE;

    if (tid == 0) ecnt = 0;

    // ---- stage A panel as bf16 (one barrier) ----
    #pragma unroll
    for (int it = 0; it < 4; ++it) {
        const int idx = it * 512 + tid;
        const int r = idx >> 5, c8 = (idx & 31) * 8;
        const float* p = spikes + (size_t)(row0 + r) * NK + c8;
        const float4 u = *reinterpret_cast<const float4*>(p);
        const float4 v = *reinterpret_cast<const float4*>(p + 4);
        const unsigned int w0 = (unsigned int)bf16_rne(u.x) | ((unsigned int)bf16_rne(u.y) << 16);
        const unsigned int w1 = (unsigned int)bf16_rne(u.z) | ((unsigned int)bf16_rne(u.w) << 16);
        const unsigned int w2 = (unsigned int)bf16_rne(v.x) | ((unsigned int)bf16_rne(v.y) << 16);
        const unsigned int w3 = (unsigned int)bf16_rne(v.z) | ((unsigned int)bf16_rne(v.w) << 16);
        *reinterpret_cast<uint4*>(&alds[r][c8]) = make_uint4(w0, w1, w2, w3);
    }
    __syncthreads();

    // ---- barrier-free K loop: 8 steps x (2 L2 B-loads + 4 ds_read + 8 MFMA) ----
    f32x4 acc[4][2];   // [mt][nt]: 64 rows x 32 cols per wave
    {
        const f32x4 z = {0.f, 0.f, 0.f, 0.f};
        #pragma unroll
        for (int mt = 0; mt < 4; ++mt) { acc[mt][0] = z; acc[mt][1] = z; }
    }
    const int a_off = (lane & 15) * 264 + (lane >> 4) * 8;       // halfs
    const int b_base = (lane >> 4) * 2048 + (wid * 32 + (lane & 15)) * 8;
    const short* alds_flat = &alds[0][0];

    #pragma unroll 2
    for (int ks = 0; ks < 8; ++ks) {
        const bf16x8 b0 = *reinterpret_cast<const bf16x8*>(wt + ks * 8192 + b_base);
        const bf16x8 b1 = *reinterpret_cast<const bf16x8*>(wt + ks * 8192 + b_base + 128);
        #pragma unroll
        for (int mt = 0; mt < 4; ++mt) {
            const bf16x8 a = *reinterpret_cast<const bf16x8*>(
                alds_flat + (mt * 16) * 264 + ks * 32 + a_off);
            acc[mt][0] = __builtin_amdgcn_mfma_f32_16x16x32_bf16(a, b0, acc[mt][0], 0, 0, 0);
            acc[mt][1] = __builtin_amdgcn_mfma_f32_16x16x32_bf16(a, b1, acc[mt][1], 0, 0, 0);
        }
    }

    // ---- decisions; in-band elements -> worklist ----
    unsigned int smask[4] = {0u, 0u, 0u, 0u};   // bit nt*4+reg
    #pragma unroll
    for (int mt = 0; mt < 4; ++mt)
        #pragma unroll
        for (int nt = 0; nt < 2; ++nt) {
            const int gcol = wid * 32 + nt * 16 + (lane & 15);
            const float bv = bias[gcol];
            #pragma unroll
            for (int reg = 0; reg < 4; ++reg) {
                const float v = acc[mt][nt][reg] + bv;
                if ((v - 0.5f) > 0.0f) smask[mt] |= 1u << (nt * 4 + reg);
                if (__builtin_expect(fabsf(v - 0.5f) < TAU, 0)) {
                    const int rl = mt * 16 + (lane >> 4) * 4 + reg;
                    const int ei = atomicAdd(&ecnt, 1);
                    if (ei < 256) elist[ei] = (unsigned int)((rl << 8) | gcol);
                }
            }
        }

    // ---- assemble row masks (one 32-bit word per row per wave) ----
    #pragma unroll
    for (int mt = 0; mt < 4; ++mt)
        #pragma unroll
        for (int reg = 0; reg < 4; ++reg) {
            const unsigned long long m0 = __ballot((smask[mt] >> (reg)) & 1u);
            const unsigned long long m1 = __ballot((smask[mt] >> (4 + reg)) & 1u);
            if (lane < 4) {
                const int g = lane;
                const unsigned int w =
                    (unsigned int)((m0 >> (g * 16)) & 0xFFFFull) |
                    ((unsigned int)((m1 >> (g * 16)) & 0xFFFFull) << 16);
                bits[mt * 16 + g * 4 + reg][wid] = w;
            }
        }
    __syncthreads();

    // ---- coalesced exact fp64 recheck (W^T; same math/order as R1..R14) ----
    const int ne = min(ecnt, 256);
    for (int e = wid; e < ne; e += 8) {
        const unsigned int pk = elist[e];
        const int rl = (int)(pk >> 8), gcol = (int)(pk & 255u);
        const float* sr = spikes + (size_t)(row0 + rl) * NK;
        const float* wc = wtT + (size_t)gcol * NK;
        const int k0 = lane * 4;
        const float4 s4 = *reinterpret_cast<const float4*>(sr + k0);
        const float4 w4 = *reinterpret_cast<const float4*>(wc + k0);
        const double p0 = (double)s4.x * (double)w4.x;
        const double p1 = (double)s4.y * (double)w4.y;
        const double p2 = (double)s4.z * (double)w4.z;
        const double p3 = (double)s4.w * (double)w4.w;
        double pl = (p0 + p1) + (p2 + p3);
        #pragma unroll
        for (int off = 32; off > 0; off >>= 1) pl += __shfl_down(pl, off);
        if (lane == 0) {
            const double vex = pl + (double)bias[gcol];
            const bool sex = (vex - 0.5) > 0.0;
            const bool spv = (bits[rl][gcol >> 5] >> (gcol & 31)) & 1u;
            if (sex != spv) atomicXor(&bits[rl][gcol >> 5], 1u << (gcol & 31));
        }
    }
    __syncthreads();

    // ---- per-row stats (identical double math to R1..R14) ----
    if (tid < MTILE) {
        int kc = 0;
        #pragma unroll
        for (int w = 0; w < 8; ++w) kc += __popc(bits[tid][w]);
        const double mu = (double)kc * (1.0 / 256.0);
        const double var = mu * (1.0 - mu);
        rinv_s[tid] = (float)(1.0 / sqrt(var + 1e-6));
        mu_s[tid] = (float)mu;
    }
    __syncthreads();

    // ---- LN epilogue + coalesced float4 store ----
    const int orow = tid >> 3;           // 0..63
    const int of0 = (tid & 7) * 4;       // 0..28
    const int grow = row0 + orow;
    const int t = grow & (NT_SEQ - 1);
    const float rinv = rinv_s[orow];
    const float muf = mu_s[orow];
    #pragma unroll
    for (int j = 0; j < 8; ++j) {
        const int f = of0 + j * 32;
        const unsigned int wb = bits[orow][j];   // f>>5 == j since of0 < 32
        const int sh = of0;
        const float4 g4 = *reinterpret_cast<const float4*>(&ln_scale[t * NF + f]);
        const float4 b4 = *reinterpret_cast<const float4*>(&ln_bias[t * NF + f]);
        float4 o;
        const float s0 = ((wb >> (sh + 0)) & 1u) ? 1.0f : 0.0f;
        const float s1 = ((wb >> (sh + 1)) & 1u) ? 1.0f : 0.0f;
        const float s2 = ((wb >> (sh + 2)) & 1u) ? 1.0f : 0.0f;
        const float s3 = ((wb >> (sh + 3)) & 1u) ? 1.0f : 0.0f;
        o.x = (s0 - muf) * rinv * g4.x + b4.x;
        o.y = (s1 - muf) * rinv * g4.y + b4.y;
        o.z = (s2 - muf) * rinv * g4.z + b4.z;
        o.w = (s3 - muf) * rinv * g4.w + b4.w;
        *reinterpret_cast<float4*>(&out[(size_t)grow * NF + f]) = o;
    }
}

extern "C" void kernel_launch(void* const* d_in, const int* in_sizes, int n_in,
                              void* d_out, int out_size, void* d_ws, size_t ws_size,
                              hipStream_t stream) {
    const float* spikes   = (const float*)d_in[0];
    const float* W        = (const float*)d_in[1];
    const float* bias     = (const float*)d_in[2];
    const float* ln_scale = (const float*)d_in[3];
    const float* ln_bias  = (const float*)d_in[4];
    float* out = (float*)d_out;
    unsigned short* wt = (unsigned short*)d_ws;                 // 128 KB
    float* wtT = (float*)((char*)d_ws + 131072);                // 256 KB fp32 W^T

    prep_w<<<dim3(256), dim3(256), 0, stream>>>(W, wt, wtT);
    lif_main<<<dim3(NROWS / MTILE), dim3(512), 0, stream>>>(
        spikes, bias, ln_scale, ln_bias, wt, wtT, out);
}